// Round 1
// baseline (542.287 us; speedup 1.0000x reference)
//
#include <hip/hip_runtime.h>
#include <hip/hip_bf16.h>

// HalfEdgeConv: out[E,256] = relu(concat(x[idx[e,0..3]]) @ W[512,256] + b)
// Strategy: bf16 split-precision MFMA GEMM (Ah*Bh + Ah*Bl + Al*Bh), since
// CDNA4 has no fp32 MFMA. W pre-split+pre-swizzled into per-K-step LDS images
// in d_ws; A (gathered x rows) staged fp32 via global_load_lds with XOR
// swizzle, split to bf16 hi/lo in-register.

#define E_ROWS 262144
#define C_IN   128
#define KN     4
#define KD     512
#define O_OUT  256
#define BM     128
#define BN     128
#define BK     32
#define NSTEPS 16      // KD / BK
#define NTHREADS 512   // 8 waves: 4 (M) x 2 (N); wave tile 32x64

typedef __attribute__((ext_vector_type(8))) short bf16x8;
typedef __attribute__((ext_vector_type(4))) float f32x4;

__device__ __forceinline__ unsigned short bf16_rne(float f) {
    unsigned u = __float_as_uint(f);
    return (unsigned short)((u + 0x7fffu + ((u >> 16) & 1u)) >> 16);
}

// Build swizzled per-K-step bf16 hi/lo images of W in ws.
// Layout: [nb(2)][step(16)][half(2)][512 chunks of 16B]
// chunk cl within an image: n_local = cl>>2, stored-pos cs = cl&3 holds
// k-chunk c = cs ^ ((n_local>>1)&3); chunk = 8 consecutive k's for one n.
__global__ void prep_w(const float* __restrict__ W, uint4* __restrict__ wimg) {
    int cid = blockIdx.x * 256 + threadIdx.x;   // 0..32767
    int cl  = cid & 511;
    int img = cid >> 9;
    int h   = img & 1;
    int s   = (img >> 1) & 15;
    int nb  = img >> 5;
    int nl  = cl >> 2;
    int cs  = cl & 3;
    int c   = cs ^ ((nl >> 1) & 3);
    int n   = nb * BN + nl;
    int kbase = s * BK + c * 8;
    unsigned short v[8];
    #pragma unroll
    for (int e = 0; e < 8; ++e) {
        float w = W[(size_t)(kbase + e) * O_OUT + n];
        unsigned u  = __float_as_uint(w);
        unsigned hb = (u + 0x7fffu + ((u >> 16) & 1u)) & 0xffff0000u; // RNE hi bits
        float r = w - __uint_as_float(hb);
        unsigned short lo = bf16_rne(r);
        unsigned short hi = (unsigned short)(hb >> 16);
        v[e] = h ? lo : hi;
    }
    uint4 o;
    o.x = (unsigned)v[0] | ((unsigned)v[1] << 16);
    o.y = (unsigned)v[2] | ((unsigned)v[3] << 16);
    o.z = (unsigned)v[4] | ((unsigned)v[5] << 16);
    o.w = (unsigned)v[6] | ((unsigned)v[7] << 16);
    wimg[cid] = o;
}

__global__ __launch_bounds__(NTHREADS, 4) void gemm(
    const float* __restrict__ x,
    const int* __restrict__ nidx,          // int32 per harness convention
    const uint4* __restrict__ wimg,
    const float* __restrict__ bias,
    float* __restrict__ out)
{
    __shared__ __align__(16) float A_s[BM * BK];              // 16 KB fp32, swizzled chunks
    __shared__ __align__(16) unsigned short B_s[2 * BN * BK]; // hi 8KB + lo 8KB
    __shared__ int   idx_s[BM * KN];                          // 2 KB
    __shared__ float b_s[BN];

    const int t  = threadIdx.x;
    const int m0 = blockIdx.x * BM;
    const int nb = blockIdx.y;
    const int n0 = nb * BN;

    idx_s[t] = nidx[(size_t)m0 * KN + t];    // BM*KN == 512 == NTHREADS
    if (t < BN) b_s[t] = bias[n0 + t];

    const int l   = t & 63;
    const int wid = t >> 6;
    const int wm  = wid >> 1;   // 0..3  (M)
    const int wn  = wid & 1;    // 0..1  (N)
    const int lr  = l & 15;
    const int lg  = l >> 4;

    // A staging constants: thread t stages chunks q=t and q=512+t.
    // LDS pos cs=q&7 of row q>>3 holds source k-chunk c = cs ^ (row&7).
    const int arow0 = t >> 3;
    const int ac0   = (t & 7) ^ (arow0 & 7);
    const int arow1 = (512 + t) >> 3;
    const int ac1   = ((512 + t) & 7) ^ (arow1 & 7);

    const uint4* wbase = wimg + (size_t)nb * (NSTEPS * 2 * 512);

    f32x4 acc[2][4];
    #pragma unroll
    for (int i = 0; i < 2; ++i)
        #pragma unroll
        for (int jj = 0; jj < 4; ++jj)
            acc[i][jj] = (f32x4){0.f, 0.f, 0.f, 0.f};

    char* Abase = (char*)&A_s[0];
    char* Bbase = (char*)&B_s[0];

    __syncthreads();

    #pragma unroll 1
    for (int s = 0; s < NSTEPS; ++s) {
        const int j  = s >> 2;          // which neighbor
        const int kc = (s & 3) << 5;    // channel base within neighbor

        // ---- stage A (gathered fp32, swizzled source -> linear LDS) ----
        {
            const float* srcA0 = x + (size_t)idx_s[arow0 * KN + j] * C_IN + kc + (ac0 << 2);
            const float* srcA1 = x + (size_t)idx_s[arow1 * KN + j] * C_IN + kc + (ac1 << 2);
            __builtin_amdgcn_global_load_lds(
                (const __attribute__((address_space(1))) void*)srcA0,
                (__attribute__((address_space(3))) void*)(Abase + (wid << 10)), 16, 0, 0);
            __builtin_amdgcn_global_load_lds(
                (const __attribute__((address_space(1))) void*)srcA1,
                (__attribute__((address_space(3))) void*)(Abase + 8192 + (wid << 10)), 16, 0, 0);
        }
        // ---- stage B (linear copy of pre-swizzled image) ----
        {
            const uint4* srcB0 = wbase + (size_t)(s * 2 + 0) * 512 + t;
            const uint4* srcB1 = wbase + (size_t)(s * 2 + 1) * 512 + t;
            __builtin_amdgcn_global_load_lds(
                (const __attribute__((address_space(1))) void*)srcB0,
                (__attribute__((address_space(3))) void*)(Bbase + (wid << 10)), 16, 0, 0);
            __builtin_amdgcn_global_load_lds(
                (const __attribute__((address_space(1))) void*)srcB1,
                (__attribute__((address_space(3))) void*)(Bbase + 8192 + (wid << 10)), 16, 0, 0);
        }
        __syncthreads();   // compiler drains vmcnt before barrier

        // ---- B fragments (bf16, one ds_read_b128 each) ----
        bf16x8 bh[4], bl[4];
        #pragma unroll
        for (int nf = 0; nf < 4; ++nf) {
            int nl  = (wn << 6) + (nf << 4) + lr;     // local col 0..127
            int cB  = lg ^ ((nl >> 1) & 3);
            int off = nl * 64 + cB * 16;
            bh[nf] = *(const bf16x8*)(Bbase + off);
            bl[nf] = *(const bf16x8*)(Bbase + 8192 + off);
        }

        // ---- A fragments: read fp32, split hi/lo, 3 MFMAs per (mf,nf) ----
        #pragma unroll
        for (int mf = 0; mf < 2; ++mf) {
            int row = (wm << 5) + (mf << 4) + lr;
            int c0  = (2 * lg)     ^ (row & 7);
            int c1  = (2 * lg + 1) ^ (row & 7);
            f32x4 a0 = *(const f32x4*)(Abase + row * 128 + c0 * 16);
            f32x4 a1 = *(const f32x4*)(Abase + row * 128 + c1 * 16);
            float av[8];
            av[0]=a0[0]; av[1]=a0[1]; av[2]=a0[2]; av[3]=a0[3];
            av[4]=a1[0]; av[5]=a1[1]; av[6]=a1[2]; av[7]=a1[3];
            bf16x8 ah, al;
            #pragma unroll
            for (int e = 0; e < 8; ++e) {
                unsigned u  = __float_as_uint(av[e]);
                unsigned hb = u & 0xffff0000u;        // truncated hi (exact split)
                ah[e] = (short)(u >> 16);
                al[e] = (short)bf16_rne(av[e] - __uint_as_float(hb));
            }
            #pragma unroll
            for (int nf = 0; nf < 4; ++nf) {
                acc[mf][nf] = __builtin_amdgcn_mfma_f32_16x16x32_bf16(ah, bh[nf], acc[mf][nf], 0, 0, 0);
                acc[mf][nf] = __builtin_amdgcn_mfma_f32_16x16x32_bf16(ah, bl[nf], acc[mf][nf], 0, 0, 0);
                acc[mf][nf] = __builtin_amdgcn_mfma_f32_16x16x32_bf16(al, bh[nf], acc[mf][nf], 0, 0, 0);
            }
        }
        __syncthreads();
    }

    // ---- epilogue: bias + relu, D layout col=lane&15, row=(lane>>4)*4+r ----
    #pragma unroll
    for (int mf = 0; mf < 2; ++mf) {
        #pragma unroll
        for (int nf = 0; nf < 4; ++nf) {
            int colL = (wn << 6) + (nf << 4) + lr;
            int col  = n0 + colL;
            float bv = b_s[colL];
            int rowb = m0 + (wm << 5) + (mf << 4) + (lg << 2);
            #pragma unroll
            for (int r = 0; r < 4; ++r) {
                float v = acc[mf][nf][r] + bv;
                out[(size_t)(rowb + r) * O_OUT + col] = fmaxf(v, 0.f);
            }
        }
    }
}

extern "C" void kernel_launch(void* const* d_in, const int* in_sizes, int n_in,
                              void* d_out, int out_size, void* d_ws, size_t ws_size,
                              hipStream_t stream) {
    const float* x    = (const float*)d_in[0];
    const int*   nidx = (const int*)d_in[1];
    const float* W    = (const float*)d_in[2];
    const float* bias = (const float*)d_in[3];
    float* out  = (float*)d_out;
    uint4* wimg = (uint4*)d_ws;   // 512 KB of ws used for W images

    hipLaunchKernelGGL(prep_w, dim3(128), dim3(256), 0, stream, W, wimg);
    hipLaunchKernelGGL(gemm, dim3(E_ROWS / BM, O_OUT / BN), dim3(NTHREADS), 0, stream,
                       x, nidx, wimg, bias, out);
}